// Round 1
// baseline (179.621 us; speedup 1.0000x reference)
//
#include <hip/hip_runtime.h>
#include <hip/hip_bf16.h>

// Problem: CrossViewFusionModule
//   global_query: [B=16, D=256] f32
//   value:        [B=16, D=256, W=128, H=128] f32
//   q = l2norm(q, axis=-1); v = l2norm(value, axis=D)
//   score[b,wh] = sum_d q[b,d]*v[b,d,wh]
//   attn = (score - min_b) / (max_b - min_b + 1e-8)   (min/max over wh per b)
//   context = attn * v
//   outputs: (context [B,D,W,H], attn [B,1,W,H]) concatenated in d_out.

#define B_  16
#define D_  256
#define WH_ 16384   // 128*128

// ---- monotone float <-> sortable uint mapping (for exact atomic min/max) ----
__device__ __forceinline__ unsigned int fmap(float f) {
    unsigned int u = __float_as_uint(f);
    return (u & 0x80000000u) ? ~u : (u | 0x80000000u);
}
__device__ __forceinline__ float funmap(unsigned int u) {
    unsigned int b = (u & 0x80000000u) ? (u ^ 0x80000000u) : ~u;
    return __uint_as_float(b);
}

__global__ void init_mm_kernel(unsigned int* __restrict__ mm) {
    int i = threadIdx.x;
    if (i < 2 * B_) mm[i] = (i & 1) ? 0u : 0xFFFFFFFFu;  // even: min-slot, odd: max-slot
}

// One block = 1024 contiguous wh positions of one b (256 threads x 4 via float4).
// grid = (WH/1024, B)
__global__ __launch_bounds__(256) void score_kernel(
    const float* __restrict__ q, const float* __restrict__ value,
    float* __restrict__ score, float* __restrict__ invn,
    unsigned int* __restrict__ mm)
{
    const int b   = blockIdx.y;
    const int tid = threadIdx.x;
    __shared__ float qs[D_];
    __shared__ float red[256];

    // ---- normalize q row in LDS ----
    float qv = q[b * D_ + tid];
    red[tid] = qv * qv;
    __syncthreads();
    for (int s = 128; s > 0; s >>= 1) {
        if (tid < s) red[tid] += red[tid + s];
        __syncthreads();
    }
    float qnorm2 = red[0];
    __syncthreads();
    qs[tid] = qv * (1.0f / fmaxf(sqrtf(qnorm2), 1e-12f));
    __syncthreads();

    // ---- per-thread: 4 wh columns, reduce over D ----
    const int wh0 = (blockIdx.x * 256 + tid) * 4;
    const float* vb = value + (size_t)b * D_ * WH_ + wh0;
    float ss0 = 0.f, ss1 = 0.f, ss2 = 0.f, ss3 = 0.f;
    float dt0 = 0.f, dt1 = 0.f, dt2 = 0.f, dt3 = 0.f;
#pragma unroll 4
    for (int d = 0; d < D_; ++d) {
        float4 v4 = *(const float4*)(vb + (size_t)d * WH_);
        float qd = qs[d];
        ss0 += v4.x * v4.x; ss1 += v4.y * v4.y;
        ss2 += v4.z * v4.z; ss3 += v4.w * v4.w;
        dt0 += qd * v4.x;   dt1 += qd * v4.y;
        dt2 += qd * v4.z;   dt3 += qd * v4.w;
    }
    float n0 = 1.0f / fmaxf(sqrtf(ss0), 1e-12f);
    float n1 = 1.0f / fmaxf(sqrtf(ss1), 1e-12f);
    float n2 = 1.0f / fmaxf(sqrtf(ss2), 1e-12f);
    float n3 = 1.0f / fmaxf(sqrtf(ss3), 1e-12f);
    float s0 = dt0 * n0, s1 = dt1 * n1, s2 = dt2 * n2, s3 = dt3 * n3;

    float4 sc4 = make_float4(s0, s1, s2, s3);
    float4 in4 = make_float4(n0, n1, n2, n3);
    *(float4*)(score + (size_t)b * WH_ + wh0) = sc4;
    *(float4*)(invn  + (size_t)b * WH_ + wh0) = in4;

    // ---- block min/max -> one atomic pair per block ----
    float mn = fminf(fminf(s0, s1), fminf(s2, s3));
    float mx = fmaxf(fmaxf(s0, s1), fmaxf(s2, s3));
    red[tid] = mn;
    __syncthreads();
    for (int s = 128; s > 0; s >>= 1) {
        if (tid < s) red[tid] = fminf(red[tid], red[tid + s]);
        __syncthreads();
    }
    float bmn = red[0];
    __syncthreads();
    red[tid] = mx;
    __syncthreads();
    for (int s = 128; s > 0; s >>= 1) {
        if (tid < s) red[tid] = fmaxf(red[tid], red[tid + s]);
        __syncthreads();
    }
    if (tid == 0) {
        atomicMin(&mm[2 * b],     fmap(bmn));
        atomicMax(&mm[2 * b + 1], fmap(red[0]));
    }
}

// Flat float4 grid-stride over B*D*WH elements.
__global__ __launch_bounds__(256) void ctx_kernel(
    const float* __restrict__ value, const float* __restrict__ score,
    const float* __restrict__ invn, const unsigned int* __restrict__ mm,
    float* __restrict__ out_ctx, float* __restrict__ out_attn)
{
    const long long N4 = (long long)B_ * D_ * WH_ / 4;  // 16,777,216
    const long long stride = (long long)gridDim.x * blockDim.x;
    for (long long i = (long long)blockIdx.x * blockDim.x + threadIdx.x;
         i < N4; i += stride) {
        int wh4 = (int)(i & (WH_ / 4 - 1));   // 4096-entry row of float4s
        int d   = (int)((i >> 12) & (D_ - 1));
        int b   = (int)(i >> 20);

        float4 v4 = ((const float4*)value)[i];
        const float4* srow = (const float4*)score + (size_t)b * (WH_ / 4);
        const float4* nrow = (const float4*)invn  + (size_t)b * (WH_ / 4);
        float4 s4 = srow[wh4];
        float4 n4 = nrow[wh4];

        float mn = funmap(mm[2 * b]);
        float mx = funmap(mm[2 * b + 1]);
        float sc = 1.0f / (mx - mn + 1e-8f);

        float4 a4;
        a4.x = (s4.x - mn) * sc; a4.y = (s4.y - mn) * sc;
        a4.z = (s4.z - mn) * sc; a4.w = (s4.w - mn) * sc;
        float4 c4;
        c4.x = a4.x * n4.x * v4.x; c4.y = a4.y * n4.y * v4.y;
        c4.z = a4.z * n4.z * v4.z; c4.w = a4.w * n4.w * v4.w;

        ((float4*)out_ctx)[i] = c4;
        if (d == 0) ((float4*)out_attn)[(size_t)b * (WH_ / 4) + wh4] = a4;
    }
}

extern "C" void kernel_launch(void* const* d_in, const int* in_sizes, int n_in,
                              void* d_out, int out_size, void* d_ws, size_t ws_size,
                              hipStream_t stream) {
    const float* q     = (const float*)d_in[0];   // [16,256]
    const float* value = (const float*)d_in[1];   // [16,256,128,128]

    float* out_ctx  = (float*)d_out;                       // B*D*WH floats
    float* out_attn = out_ctx + (size_t)B_ * D_ * WH_;     // B*WH floats

    // workspace layout: score [B*WH] f32 | invn [B*WH] f32 | mm [2*B] u32
    float* score = (float*)d_ws;
    float* invn  = score + (size_t)B_ * WH_;
    unsigned int* mm = (unsigned int*)(invn + (size_t)B_ * WH_);

    hipLaunchKernelGGL(init_mm_kernel, dim3(1), dim3(64), 0, stream, mm);
    hipLaunchKernelGGL(score_kernel, dim3(WH_ / 1024, B_), dim3(256), 0, stream,
                       q, value, score, invn, mm);
    hipLaunchKernelGGL(ctx_kernel, dim3(4096), dim3(256), 0, stream,
                       value, score, invn, mm, out_ctx, out_attn);
}